// Round 14
// baseline (4854.648 us; speedup 1.0000x reference)
//
#include <hip/hip_runtime.h>
#include <hip/hip_fp16.h>

#define NUM_USERS 100000
#define NUM_ITEMS 50000
#define NN (NUM_USERS + NUM_ITEMS)
#define EMB_DIM 64
#define BATCH 16384
#define RPA 586                       // rows per super-bucket
#define NBA 256                       // super-buckets == CU count
#define SLOT 24576                    // cv_tmp slot per bucket (mean 18750 + pad 3584 + margin)
#define NBLKA 512                     // binA blocks (2/CU at ~61KB LDS)
#define SDEPTH 28                     // staging depth per bucket
#define SENT (1 << 28)                // sentinel flag for padding holes
#define LSTR 68                       // LDS accumulator row stride (floats; 64+4 pad)

__device__ __forceinline__ unsigned h2u(__half2 h) {
    union { __half2 h; unsigned u; } x; x.h = h; return x.u;
}
__device__ __forceinline__ __half2 u2h(unsigned u) {
    union { __half2 h; unsigned u; } x; x.u = u; return x.h;
}

// init: E0 = concat(user_emb, item_emb) quantized fp16; seeds gq.
__global__ void lgcn_init(const float4* __restrict__ user_emb,
                          const float4* __restrict__ item_emb,
                          uint2* __restrict__ embh,
                          unsigned long long* __restrict__ gq,
                          int n_user4, int n_tot4) {
    int i = blockIdx.x * blockDim.x + threadIdx.x;
    if (i < NBA) gq[i] = (unsigned long long)(unsigned)(i * SLOT);
    if (i >= n_tot4) return;
    float4 v = (i < n_user4) ? user_emb[i] : item_emb[i - n_user4];
    __half2 lo = __float22half2_rn(make_float2(v.x, v.y));
    __half2 hi = __float22half2_rn(make_float2(v.z, v.w));
    uint2 o;
    o.x = h2u(lo);
    o.y = h2u(hi);
    embh[i] = o;
}

// binA: super-bucket scatter with LDS write-combining. Stages each bucket's
// stream in a 28-deep LDS ring; after each 512-edge round, owner threads
// flush complete 8-entry (64B) chunks as aligned int4 stores.
// Packs {row_local10<<18 | col, half2(val,val)}; claims padded to 8 with
// SENT holes. This is the ONLY binning pass (no exact CSR anymore).
__global__ void __launch_bounds__(512) lgcn_binA(
        const int* __restrict__ rows, const int* __restrict__ cols,
        const float* __restrict__ vals, unsigned long long* __restrict__ gq,
        int2* __restrict__ cv_tmp, int nnz, int epb) {
    __shared__ int2 stage[NBA][SDEPTH];   // 57.3 KB
    __shared__ int hist[NBA];
    __shared__ int gbase[NBA];
    __shared__ int scnt[NBA];
    __shared__ int flushed[NBA];
    int t = threadIdx.x;
    int base = blockIdx.x * epb;
    int end  = base + epb; if (end > nnz) end = nnz;
    if (t < NBA) { hist[t] = 0; scnt[t] = 0; flushed[t] = 0; }
    __syncthreads();
    for (int i = base + t; i < end; i += 512)
        atomicAdd(&hist[(unsigned)rows[i] / RPA], 1);
    __syncthreads();
    if (t < NBA) {
        int c = hist[t];
        int p = 0;
        if (c) {
            int cp = (c + 7) & ~7;       // line-align the claim
            unsigned long long old = atomicAdd(&gq[t],
                ((unsigned long long)c << 32) | (unsigned)cp);
            p = (int)(unsigned)old;
        }
        gbase[t] = p;
    }
    __syncthreads();
    for (int r0 = base; r0 < end; r0 += 512) {
        int i = r0 + t;
        if (i < end) {
            int r = rows[i];
            int b = (unsigned)r / RPA;
            int rl = r - b * RPA;
            int k = atomicAdd(&scnt[b], 1);
            __half hv = __float2half(vals[i]);
            stage[b][k % SDEPTH] = make_int2((rl << 18) | cols[i],
                                             (int)h2u(__half2half2(hv)));
        }
        __syncthreads();
        if (t < NBA) {
            int s = flushed[t], c = scnt[t];
            int gb = gbase[t];
            while (c - s >= 8) {
                int4* dst = (int4*)&cv_tmp[gb + s];
#pragma unroll
                for (int j = 0; j < 8; j += 2) {
                    int2 e0 = stage[t][(s + j) % SDEPTH];
                    int2 e1 = stage[t][(s + j + 1) % SDEPTH];
                    dst[j >> 1] = make_int4(e0.x, e0.y, e1.x, e1.y);
                }
                s += 8;
            }
            flushed[t] = s;
        }
        __syncthreads();
    }
    if (t < NBA) {
        int s = flushed[t], c = scnt[t];
        int cp = (c + 7) & ~7;
        int gb = gbase[t];
        for (int j = s; j < c; ++j) cv_tmp[gb + j] = stage[t][j % SDEPTH];
        for (int j = c; j < cp; ++j) cv_tmp[gb + j] = make_int2(SENT, 0);
    }
}

// ---- bucket SpMM: one block per super-bucket (256 blocks = 256 CUs),
// 1024 threads, fp32 LDS accumulator 586 rows x 68 floats (159.4 KB).
// Edges stream coalesced from the bucket window (no row sorting needed);
// 4 edge-groups x 16 dim-lanes, 8B gathers, x8 unroll; products accumulate
// via ds_add_f32; dense fp32->fp16 writeout. row_ptr/cv never built.
__global__ void __launch_bounds__(1024) lgcn_spmm(
        const unsigned long long* __restrict__ gq,
        const int2* __restrict__ win,
        const uint2* __restrict__ embh,
        uint4* __restrict__ nxth) {
    __shared__ float acc[RPA * LSTR];   // 159,392 B
    int b = blockIdx.x;
    long long base = (long long)b * SLOT;
    int wlen = (int)(unsigned)gq[b] - b * SLOT;   // window length incl. holes
    int t = threadIdx.x;
    for (int i = t; i < RPA * LSTR; i += 1024) acc[i] = 0.f;
    __syncthreads();

    int wave = t >> 6, lane = t & 63;
    int grp  = lane >> 4;     // 0..3 edge group
    int dim4 = lane & 15;     // 8B (4-half) slice of the 64-dim row

    for (int i0 = wave * 32; i0 < wlen; i0 += 16 * 32) {
        int2 p[8]; uint2 raw[8];
#pragma unroll
        for (int j = 0; j < 8; ++j) {
            int e = i0 + j * 4 + grp;
            p[j] = (e < wlen) ? win[base + e] : make_int2(SENT, 0);
        }
#pragma unroll
        for (int j = 0; j < 8; ++j)
            raw[j] = (p[j].x & SENT) ? make_uint2(0, 0)
                     : embh[(long long)(p[j].x & 0x3FFFF) * 16 + dim4];
#pragma unroll
        for (int j = 0; j < 8; ++j) {
            if (p[j].x & SENT) continue;
            float v = __half2float(__low2half(u2h((unsigned)p[j].y)));
            float2 f0 = __half22float2(u2h(raw[j].x));
            float2 f1 = __half22float2(u2h(raw[j].y));
            int rl = ((unsigned)p[j].x) >> 18;
            float* d = &acc[rl * LSTR + dim4 * 4];
            atomicAdd(d + 0, v * f0.x);
            atomicAdd(d + 1, v * f0.y);
            atomicAdd(d + 2, v * f1.x);
            atomicAdd(d + 3, v * f1.y);
        }
    }
    __syncthreads();

    // writeout: 586 rows x 8 uint4 (128B/row), fp32 -> fp16
    int r0 = b * RPA;
    for (int i = t; i < RPA * 8; i += 1024) {
        int rl = i >> 3, q = i & 7;
        int r = r0 + rl;
        if (r < NN) {
            const float* s = &acc[rl * LSTR + q * 8];
            uint4 o;
            o.x = h2u(__floats2half2_rn(s[0], s[1]));
            o.y = h2u(__floats2half2_rn(s[2], s[3]));
            o.z = h2u(__floats2half2_rn(s[4], s[5]));
            o.w = h2u(__floats2half2_rn(s[6], s[7]));
            nxth[(long long)r * 8 + q] = o;
        }
    }
}

// out[b] = dot(sum_l E_l[u], sum_l E_l[NUM_USERS+i]) / 16 ; 16 lanes/output.
__global__ void lgcn_dot(const uint2* __restrict__ E0, const uint2* __restrict__ E1,
                         const uint2* __restrict__ E2, const uint2* __restrict__ E3,
                         const int* __restrict__ user_idx,
                         const int* __restrict__ item_idx,
                         float* __restrict__ out, int batch) {
    int t = blockIdx.x * blockDim.x + threadIdx.x;
    int b = t >> 4;
    if (b >= batch) return;
    int l = t & 15;
    long long ru = (long long)user_idx[b] * 16 + l;
    long long ri = (long long)(NUM_USERS + item_idx[b]) * 16 + l;
    float4 su = {0.f, 0.f, 0.f, 0.f};
    float4 si = {0.f, 0.f, 0.f, 0.f};
    const uint2* Es[4] = {E0, E1, E2, E3};
#pragma unroll
    for (int q = 0; q < 4; ++q) {
        uint2 a = Es[q][ru];
        uint2 c = Es[q][ri];
        float2 a0 = __half22float2(u2h(a.x)), a1 = __half22float2(u2h(a.y));
        float2 c0 = __half22float2(u2h(c.x)), c1 = __half22float2(u2h(c.y));
        su.x += a0.x; su.y += a0.y; su.z += a1.x; su.w += a1.y;
        si.x += c0.x; si.y += c0.y; si.z += c1.x; si.w += c1.y;
    }
    float s = su.x * si.x + su.y * si.y + su.z * si.z + su.w * si.w;
    s += __shfl_down(s, 8, 16);
    s += __shfl_down(s, 4, 16);
    s += __shfl_down(s, 2, 16);
    s += __shfl_down(s, 1, 16);
    if (l == 0) out[b] = s * (1.0f / 16.0f);
}

extern "C" void kernel_launch(void* const* d_in, const int* in_sizes, int n_in,
                              void* d_out, int out_size, void* d_ws, size_t ws_size,
                              hipStream_t stream) {
    const float* user_emb = (const float*)d_in[0];
    const float* item_emb = (const float*)d_in[1];
    const int*   rows     = (const int*)d_in[2];
    const int*   cols     = (const int*)d_in[3];
    const float* vals     = (const float*)d_in[4];
    const int*   user_idx = (const int*)d_in[5];
    const int*   item_idx = (const int*)d_in[6];
    float* out = (float*)d_out;

    const int nnz = in_sizes[2];
    const size_t node_uint2 = (size_t)NN * 16;            // 2.4M uint2 per table

    // workspace: E0..E3 fp16 (4 x 19.2MB) | cv_tmp slotted (50.3MB) | gq
    uint2* E[4];
    E[0] = (uint2*)d_ws;
    E[1] = E[0] + node_uint2;
    E[2] = E[1] + node_uint2;
    E[3] = E[2] + node_uint2;
    int2*  cv_tmp  = (int2*)(E[3] + node_uint2);
    unsigned long long* gq = (unsigned long long*)(cv_tmp + (size_t)NBA * SLOT);

    const int n_tot4  = NN * EMB_DIM / 4;
    const int n_user4 = NUM_USERS * EMB_DIM / 4;
    const int epb = (nnz + NBLKA - 1) / NBLKA;            // 9375

    lgcn_init<<<(n_tot4 + 255) / 256, 256, 0, stream>>>(
        (const float4*)user_emb, (const float4*)item_emb,
        E[0], gq, n_user4, n_tot4);

    lgcn_binA<<<NBLKA, 512, 0, stream>>>(rows, cols, vals, gq, cv_tmp, nnz, epb);

    // 3 layers of bucket SpMM: E0 -> E1 -> E2 -> E3 (no CSR, no row_ptr)
    for (int layer = 0; layer < 3; ++layer) {
        lgcn_spmm<<<NBA, 1024, 0, stream>>>(gq, cv_tmp,
                                            E[layer], (uint4*)E[layer + 1]);
    }

    lgcn_dot<<<(BATCH * 16 + 255) / 256, 256, 0, stream>>>(
        E[0], E[1], E[2], E[3], user_idx, item_idx, out, BATCH);
}

// Round 15
// 499.966 us; speedup vs baseline: 9.7100x; 9.7100x over previous
//
#include <hip/hip_runtime.h>
#include <hip/hip_fp16.h>

#define NUM_USERS 100000
#define NUM_ITEMS 50000
#define NN (NUM_USERS + NUM_ITEMS)
#define EMB_DIM 64
#define BATCH 16384
#define RPA 512                       // rows per super-bucket (binA staging)
#define NBA ((NN + RPA - 1) / RPA)    // 293 super-buckets
#define RPB 256                       // rows per fine bucket (CSR/binB)
#define NBB ((NN + RPB - 1) / RPB)    // 586 fine buckets
#define SLOT 20480                    // cv_tmp slot per super-bucket (mean 16384)
#define NBLKA 512                     // binA blocks (2/CU at ~58KB LDS)
#define SDEPTH 24                     // staging depth per bucket
#define SENT (1 << 27)                // sentinel flag for padding holes

__device__ __forceinline__ unsigned h2u(__half2 h) {
    union { __half2 h; unsigned u; } x; x.h = h; return x.u;
}
__device__ __forceinline__ __half2 u2h(unsigned u) {
    union { __half2 h; unsigned u; } x; x.u = u; return x.h;
}

// binA with fused init: prologue converts E0 to fp16 (grid-stride), then
// super-bucket scatter with LDS write-combining. gq is zero-initialized by
// memset; claims use RELATIVE cursors (abs = b*SLOT + rel), so no seed
// kernel and no cross-block ordering hazard.
// Packs {row_local9<<18 | col, val_fp32}; claims padded to 8 w/ SENT holes.
__global__ void __launch_bounds__(512) lgcn_binA(
        const float4* __restrict__ user_emb, const float4* __restrict__ item_emb,
        uint2* __restrict__ embh, int n_user4, int n_tot4,
        const int* __restrict__ rows, const int* __restrict__ cols,
        const float* __restrict__ vals, unsigned long long* __restrict__ gq,
        int2* __restrict__ cv_tmp, int nnz, int epb) {
    __shared__ int2 stage[NBA][SDEPTH];   // 56.3 KB
    __shared__ int hist[NBA];
    __shared__ int gbase[NBA];
    __shared__ int scnt[NBA];
    __shared__ int flushed[NBA];
    int t = threadIdx.x;

    // fused init: E0 = fp16(concat(user_emb, item_emb))
    for (int i = blockIdx.x * 512 + t; i < n_tot4; i += NBLKA * 512) {
        float4 v = (i < n_user4) ? user_emb[i] : item_emb[i - n_user4];
        uint2 o;
        o.x = h2u(__float22half2_rn(make_float2(v.x, v.y)));
        o.y = h2u(__float22half2_rn(make_float2(v.z, v.w)));
        embh[i] = o;
    }

    int base = blockIdx.x * epb;
    int end  = base + epb; if (end > nnz) end = nnz;
    if (t < NBA) { hist[t] = 0; scnt[t] = 0; flushed[t] = 0; }
    __syncthreads();
    for (int i = base + t; i < end; i += 512)
        atomicAdd(&hist[rows[i] >> 9], 1);
    __syncthreads();
    if (t < NBA) {
        int c = hist[t];
        int p = 0;
        if (c) {
            int cp = (c + 7) & ~7;       // line-align the claim
            unsigned long long old = atomicAdd(&gq[t],
                ((unsigned long long)c << 32) | (unsigned)cp);
            p = (int)(unsigned)old;      // relative padded cursor
        }
        gbase[t] = t * SLOT + p;         // absolute base
    }
    __syncthreads();
    for (int r0 = base; r0 < end; r0 += 512) {
        int i = r0 + t;
        if (i < end) {
            int r = rows[i];
            int b = r >> 9;
            int k = atomicAdd(&scnt[b], 1);
            stage[b][k % SDEPTH] = make_int2(((r & 511) << 18) | cols[i],
                                             __float_as_int(vals[i]));
        }
        __syncthreads();
        if (t < NBA) {
            int s = flushed[t], c = scnt[t];
            int gb = gbase[t];
            while (c - s >= 8) {
                int4* dst = (int4*)&cv_tmp[gb + s];
#pragma unroll
                for (int j = 0; j < 8; j += 2) {
                    int2 e0 = stage[t][(s + j) % SDEPTH];
                    int2 e1 = stage[t][(s + j + 1) % SDEPTH];
                    dst[j >> 1] = make_int4(e0.x, e0.y, e1.x, e1.y);
                }
                s += 8;
            }
            flushed[t] = s;
        }
        __syncthreads();
    }
    if (t < NBA) {
        int s = flushed[t], c = scnt[t];
        int cp = (c + 7) & ~7;
        int gb = gbase[t];
        for (int j = s; j < c; ++j) cv_tmp[gb + j] = stage[t][j % SDEPTH];
        for (int j = c; j < cp; ++j) cv_tmp[gb + j] = make_int2(SENT, 0);
    }
}

// binB: one workgroup per FINE bucket (256 rows). Computes its own global
// base by reducing gq counts, scans its super-bucket's window filtering on
// parity bit, LDS-hist + scan -> row_ptr, scatters into exact CSR with val
// pre-packed as half2(v,v).
__global__ void __launch_bounds__(512) lgcn_binB(
        const unsigned long long* __restrict__ gq,
        const int2* __restrict__ cv_tmp, int2* __restrict__ cv,
        int* __restrict__ row_ptr, int nnz) {
    __shared__ int hist[RPB];
    __shared__ int pfx[RPB];
    __shared__ int cur[RPB];
    __shared__ int red[512];
    __shared__ int mybase;
    int j = blockIdx.x;
    int s = j >> 1;
    int par = j & 1;
    int t = threadIdx.x;
    if (j == 0 && t == 0) row_ptr[NN] = nnz;
    long long w0 = (long long)s * SLOT;
    unsigned long long q = gq[s];
    int wlen = (int)(unsigned)q;              // padded window length (relative)
    int stot = (int)(q >> 32);                // real edges in super-bucket
    int r0 = j * RPB;
    int nrows = NN - r0; if (nrows > RPB) nrows = RPB;

    // bucket base = sum of counts of super-buckets < s (folded bscan)
    int partial = 0;
    for (int i = t; i < NBA; i += 512)
        if (i < s) partial += (int)(gq[i] >> 32);
    red[t] = partial;
    if (t < RPB) hist[t] = 0;
    __syncthreads();
    for (int off = 256; off > 0; off >>= 1) {
        if (t < off) red[t] += red[t + off];
        __syncthreads();
    }
    int base_s = red[0];

    for (int i = t; i < wlen; i += 512) {
        int x = cv_tmp[w0 + i].x;
        if (!(x & SENT) && (((x >> 26) & 1) == par))
            atomicAdd(&hist[(x >> 18) & 255], 1);
    }
    __syncthreads();
    if (t < RPB) pfx[t] = hist[t];
    __syncthreads();
    for (int off = 1; off < RPB; off <<= 1) {
        int x = 0;
        if (t < RPB && t >= off) x = pfx[t - off];
        __syncthreads();
        if (t < RPB) pfx[t] += x;
        __syncthreads();
    }
    if (t == 0) {
        int myt = pfx[RPB - 1];
        mybase = base_s + (par ? (stot - myt) : 0);
    }
    __syncthreads();
    if (t < RPB) {
        int excl = mybase + pfx[t] - hist[t];
        cur[t] = excl;
        if (t < nrows) row_ptr[r0 + t] = excl;
    }
    __syncthreads();
    for (int i = t; i < wlen; i += 512) {
        int2 p = cv_tmp[w0 + i];
        int x = p.x;
        if ((x & SENT) || (((x >> 26) & 1) != par)) continue;
        int rl = (x >> 18) & 255;
        int pos = atomicAdd(&cur[rl], 1);
        __half hv = __float2half(__int_as_float(p.y));
        cv[pos] = make_int2(x & 0x3FFFF, (int)h2u(__half2half2(hv)));
    }
}

// ---- gather SpMM, all-fp16 datapath: one wave per row; 8 edge-groups x 8
// lanes; lane owns 16B (8 halves). Accumulate in __half2 via v_pk_fma_f16,
// reduce in __hadd2, store directly. x4 then x2 unroll for MLP.
__global__ void __launch_bounds__(256) lgcn_spmm(
        const int* __restrict__ row_ptr,
        const int2* __restrict__ cv,
        const uint4* __restrict__ embh,
        uint4* __restrict__ nxth) {
    int wid = (blockIdx.x * blockDim.x + threadIdx.x) >> 6;
    int lane = threadIdx.x & 63;
    if (wid >= NN) return;
    int start = row_ptr[wid];
    int n = row_ptr[wid + 1] - start;
    int grp  = lane >> 3;    // 0..7 edge group
    int dim8 = lane & 7;     // 16B (8-half) slice index
    const int2* ep = cv + start;

    __half2 c0 = __float2half2_rn(0.f);
    __half2 c1 = c0, c2 = c0, c3 = c0;
    int m = n >> 3;          // rounds where all 8 groups have an edge
    int k = 0;
    for (; k + 4 <= m; k += 4) {
        int2 p[4]; uint4 raw[4];
#pragma unroll
        for (int j = 0; j < 4; ++j) p[j] = ep[8 * (k + j) + grp];
#pragma unroll
        for (int j = 0; j < 4; ++j)
            raw[j] = embh[(long long)p[j].x * 8 + dim8];
#pragma unroll
        for (int j = 0; j < 4; ++j) {
            __half2 v2 = u2h((unsigned)p[j].y);
            c0 = __hfma2(v2, u2h(raw[j].x), c0);
            c1 = __hfma2(v2, u2h(raw[j].y), c1);
            c2 = __hfma2(v2, u2h(raw[j].z), c2);
            c3 = __hfma2(v2, u2h(raw[j].w), c3);
        }
    }
    for (; k + 2 <= m; k += 2) {
        int2 p[2]; uint4 raw[2];
#pragma unroll
        for (int j = 0; j < 2; ++j) p[j] = ep[8 * (k + j) + grp];
#pragma unroll
        for (int j = 0; j < 2; ++j)
            raw[j] = embh[(long long)p[j].x * 8 + dim8];
#pragma unroll
        for (int j = 0; j < 2; ++j) {
            __half2 v2 = u2h((unsigned)p[j].y);
            c0 = __hfma2(v2, u2h(raw[j].x), c0);
            c1 = __hfma2(v2, u2h(raw[j].y), c1);
            c2 = __hfma2(v2, u2h(raw[j].z), c2);
            c3 = __hfma2(v2, u2h(raw[j].w), c3);
        }
    }
    for (; k < m; ++k) {
        int2 p = ep[8 * k + grp];
        uint4 raw = embh[(long long)p.x * 8 + dim8];
        __half2 v2 = u2h((unsigned)p.y);
        c0 = __hfma2(v2, u2h(raw.x), c0);
        c1 = __hfma2(v2, u2h(raw.y), c1);
        c2 = __hfma2(v2, u2h(raw.z), c2);
        c3 = __hfma2(v2, u2h(raw.w), c3);
    }
    int rem = n & 7;
    if (grp < rem) {
        int2 p = ep[8 * m + grp];
        uint4 raw = embh[(long long)p.x * 8 + dim8];
        __half2 v2 = u2h((unsigned)p.y);
        c0 = __hfma2(v2, u2h(raw.x), c0);
        c1 = __hfma2(v2, u2h(raw.y), c1);
        c2 = __hfma2(v2, u2h(raw.z), c2);
        c3 = __hfma2(v2, u2h(raw.w), c3);
    }

    // reduce the 8 edge-groups onto group 0 (lanes 0..7), packed fp16
#pragma unroll
    for (int off = 8; off < 64; off <<= 1) {
        c0 = __hadd2(c0, u2h(__shfl_xor(h2u(c0), off)));
        c1 = __hadd2(c1, u2h(__shfl_xor(h2u(c1), off)));
        c2 = __hadd2(c2, u2h(__shfl_xor(h2u(c2), off)));
        c3 = __hadd2(c3, u2h(__shfl_xor(h2u(c3), off)));
    }
    if (grp == 0) {
        long long o = (long long)wid * 8 + dim8;
        uint4 ov;
        ov.x = h2u(c0); ov.y = h2u(c1); ov.z = h2u(c2); ov.w = h2u(c3);
        nxth[o] = ov;
    }
}

// out[b] = dot(sum_l E_l[u], sum_l E_l[NUM_USERS+i]) / 16 ; 16 lanes/output.
__global__ void lgcn_dot(const uint2* __restrict__ E0, const uint2* __restrict__ E1,
                         const uint2* __restrict__ E2, const uint2* __restrict__ E3,
                         const int* __restrict__ user_idx,
                         const int* __restrict__ item_idx,
                         float* __restrict__ out, int batch) {
    int t = blockIdx.x * blockDim.x + threadIdx.x;
    int b = t >> 4;
    if (b >= batch) return;
    int l = t & 15;
    long long ru = (long long)user_idx[b] * 16 + l;
    long long ri = (long long)(NUM_USERS + item_idx[b]) * 16 + l;
    float4 su = {0.f, 0.f, 0.f, 0.f};
    float4 si = {0.f, 0.f, 0.f, 0.f};
    const uint2* Es[4] = {E0, E1, E2, E3};
#pragma unroll
    for (int q = 0; q < 4; ++q) {
        uint2 a = Es[q][ru];
        uint2 c = Es[q][ri];
        float2 a0 = __half22float2(u2h(a.x)), a1 = __half22float2(u2h(a.y));
        float2 c0 = __half22float2(u2h(c.x)), c1 = __half22float2(u2h(c.y));
        su.x += a0.x; su.y += a0.y; su.z += a1.x; su.w += a1.y;
        si.x += c0.x; si.y += c0.y; si.z += c1.x; si.w += c1.y;
    }
    float s = su.x * si.x + su.y * si.y + su.z * si.z + su.w * si.w;
    s += __shfl_down(s, 8, 16);
    s += __shfl_down(s, 4, 16);
    s += __shfl_down(s, 2, 16);
    s += __shfl_down(s, 1, 16);
    if (l == 0) out[b] = s * (1.0f / 16.0f);
}

extern "C" void kernel_launch(void* const* d_in, const int* in_sizes, int n_in,
                              void* d_out, int out_size, void* d_ws, size_t ws_size,
                              hipStream_t stream) {
    const float* user_emb = (const float*)d_in[0];
    const float* item_emb = (const float*)d_in[1];
    const int*   rows     = (const int*)d_in[2];
    const int*   cols     = (const int*)d_in[3];
    const float* vals     = (const float*)d_in[4];
    const int*   user_idx = (const int*)d_in[5];
    const int*   item_idx = (const int*)d_in[6];
    float* out = (float*)d_out;

    const int nnz = in_sizes[2];
    const size_t node_uint2 = (size_t)NN * 16;            // 2.4M uint2 per table

    // workspace: E0..E3 fp16 (4 x 19.2MB) | cv (38.4) | cv_tmp (48) | ints
    uint2* E[4];
    E[0] = (uint2*)d_ws;
    E[1] = E[0] + node_uint2;
    E[2] = E[1] + node_uint2;
    E[3] = E[2] + node_uint2;
    int2*  cv      = (int2*)(E[3] + node_uint2);
    int2*  cv_tmp  = cv + nnz;
    unsigned long long* gq = (unsigned long long*)(cv_tmp + (size_t)NBA * SLOT);
    int*   row_ptr = (int*)(gq + NBA);                    // NN+1

    const int n_tot4  = NN * EMB_DIM / 4;
    const int n_user4 = NUM_USERS * EMB_DIM / 4;
    const int epb = (nnz + NBLKA - 1) / NBLKA;            // 9375

    hipMemsetAsync(gq, 0, NBA * sizeof(unsigned long long), stream);

    lgcn_binA<<<NBLKA, 512, 0, stream>>>(
        (const float4*)user_emb, (const float4*)item_emb, E[0],
        n_user4, n_tot4, rows, cols, vals, gq, cv_tmp, nnz, epb);

    lgcn_binB<<<NBB, 512, 0, stream>>>(gq, cv_tmp, cv, row_ptr, nnz);

    // 3 layers of gather SpMM: E0 -> E1 -> E2 -> E3
    const int spmm_blocks = (NN * 64 + 255) / 256;   // one wave per row
    for (int layer = 0; layer < 3; ++layer) {
        lgcn_spmm<<<spmm_blocks, 256, 0, stream>>>(row_ptr, cv,
                                                   (const uint4*)E[layer],
                                                   (uint4*)E[layer + 1]);
    }

    lgcn_dot<<<(BATCH * 16 + 255) / 256, 256, 0, stream>>>(
        E[0], E[1], E[2], E[3], user_idx, item_idx, out, BATCH);
}